// Round 1
// baseline (498.737 us; speedup 1.0000x reference)
//
#include <hip/hip_runtime.h>
#include <hip/hip_bf16.h>
#include <math.h>

#define N_VOTERS 1048576
#define NUM_CAND 32
#define EMB 128
#define NUM_ELEC 4096

typedef unsigned short u16;
typedef __attribute__((ext_vector_type(8))) short bf16x8;
typedef __attribute__((ext_vector_type(4))) float f32x4;

__device__ __forceinline__ u16 f2bf(float f) {
    union { float f; unsigned u; } v; v.f = f;
    unsigned r = v.u + 0x7FFFu + ((v.u >> 16) & 1u);
    return (u16)(r >> 16);
}
__device__ __forceinline__ float bf2f(u16 h) {
    union { unsigned u; float f; } v; v.u = ((unsigned)h) << 16;
    return v.f;
}

// ---------------- Kernel A: transpose+convert local weights to bf16 ----------------
// w1t: [128][32]  (n-major)   w2t/w3t: [128][128] (n-major)
__global__ void prep_weights(const float* __restrict__ lW1, const float* __restrict__ lW2,
                             const float* __restrict__ lW3,
                             u16* __restrict__ w1t, u16* __restrict__ w2t, u16* __restrict__ w3t) {
    int tid = blockIdx.x * blockDim.x + threadIdx.x;  // 0..16383
    if (tid < 4096) {
        int n = tid >> 5, k = tid & 31;
        w1t[tid] = f2bf(lW1[k * EMB + n]);            // lW1 is [32][128]
    }
    {
        int n = tid >> 7, k = tid & 127;
        w2t[tid] = f2bf(lW2[k * EMB + n]);            // lW2 is [128][128]
        w3t[tid] = f2bf(lW3[k * EMB + n]);
    }
}

// ---------------- Kernel B: fused local MLP (bf16 MFMA) + in-block segment sum ----------------
// Block: 256 threads = 4 waves, M=128 voters. Wave w owns col tiles {2w, 2w+1} (cols 32w..32w+31).
// LDS: two bf16 act buffers [128][136] (ping-pong), aliased as fp32 h3 [128][132] at the end.
__global__ __launch_bounds__(256, 2) void local_fused(
    const float* __restrict__ x, const int* __restrict__ idx,
    const float* __restrict__ lb1, const float* __restrict__ lb2, const float* __restrict__ lb3,
    const u16* __restrict__ w1t, const u16* __restrict__ w2t, const u16* __restrict__ w3t,
    float* __restrict__ agg)
{
    constexpr int STR = 136;  // u16 stride: 272B/row => row bank-step 4 (mod 32), balanced b128 reads
    __shared__ __align__(16) u16 smem[2 * 128 * STR];   // 69632 B
    __shared__ int segs[128];
    u16* bufA = smem;
    u16* bufB = smem + 128 * STR;
    float* h3 = (float*)smem;                            // stride 132 floats (67584 B <= 69632)

    const int tid = threadIdx.x;
    const int v0 = blockIdx.x * 128;

    // ---- stage x tile [128][32] fp32 -> bf16 LDS ----
    {
        const float4* xin = (const float4*)(x + (size_t)v0 * NUM_CAND);
        #pragma unroll
        for (int i = 0; i < 4; ++i) {
            int f = i * 256 + tid;                 // float4 id 0..1023
            float4 v = xin[f];
            int row = f >> 3, col = (f & 7) * 4;
            unsigned p0 = (unsigned)f2bf(v.x) | ((unsigned)f2bf(v.y) << 16);
            unsigned p1 = (unsigned)f2bf(v.z) | ((unsigned)f2bf(v.w) << 16);
            uint2 pv; pv.x = p0; pv.y = p1;
            *(uint2*)(bufA + row * STR + col) = pv;
        }
        if (tid < 128) segs[tid] = idx[v0 + tid];
    }
    __syncthreads();

    const int lane = tid & 63;
    const int wv = tid >> 6;        // wave 0..3
    const int qd = lane >> 4;       // quad
    const int l15 = lane & 15;
    const int c0 = wv * 32 + l15;   // output col, tile 0
    const int c1 = c0 + 16;         // output col, tile 1

    // ---- layer 1 (K=32): bufA -> bufB, +b1, relu ----
    {
        bf16x8 b0 = *(const bf16x8*)(w1t + (wv * 32 + l15) * 32 + qd * 8);
        bf16x8 b1 = *(const bf16x8*)(w1t + (wv * 32 + 16 + l15) * 32 + qd * 8);
        float bias0 = lb1[c0], bias1 = lb1[c1];
        #pragma unroll
        for (int s = 0; s < 8; ++s) {
            bf16x8 a = *(const bf16x8*)(bufA + (s * 16 + l15) * STR + qd * 8);
            f32x4 acc0 = {0.f, 0.f, 0.f, 0.f}, acc1 = {0.f, 0.f, 0.f, 0.f};
            acc0 = __builtin_amdgcn_mfma_f32_16x16x32_bf16(a, b0, acc0, 0, 0, 0);
            acc1 = __builtin_amdgcn_mfma_f32_16x16x32_bf16(a, b1, acc1, 0, 0, 0);
            #pragma unroll
            for (int r = 0; r < 4; ++r) {
                int row = s * 16 + qd * 4 + r;
                float u0 = acc0[r] + bias0; u0 = u0 > 0.f ? u0 : 0.f;
                float u1 = acc1[r] + bias1; u1 = u1 > 0.f ? u1 : 0.f;
                bufB[row * STR + c0] = f2bf(u0);
                bufB[row * STR + c1] = f2bf(u1);
            }
        }
    }
    __syncthreads();

    // ---- layer 2 (K=128): bufB -> bufA, +b2, relu ----
    {
        bf16x8 wb[2][4];
        #pragma unroll
        for (int t = 0; t < 2; ++t)
            #pragma unroll
            for (int kk = 0; kk < 4; ++kk)
                wb[t][kk] = *(const bf16x8*)(w2t + (wv * 32 + t * 16 + l15) * 128 + kk * 32 + qd * 8);
        float bias0 = lb2[c0], bias1 = lb2[c1];
        #pragma unroll
        for (int s = 0; s < 8; ++s) {
            f32x4 acc0 = {0.f, 0.f, 0.f, 0.f}, acc1 = {0.f, 0.f, 0.f, 0.f};
            #pragma unroll
            for (int kk = 0; kk < 4; ++kk) {
                bf16x8 a = *(const bf16x8*)(bufB + (s * 16 + l15) * STR + kk * 32 + qd * 8);
                acc0 = __builtin_amdgcn_mfma_f32_16x16x32_bf16(a, wb[0][kk], acc0, 0, 0, 0);
                acc1 = __builtin_amdgcn_mfma_f32_16x16x32_bf16(a, wb[1][kk], acc1, 0, 0, 0);
            }
            #pragma unroll
            for (int r = 0; r < 4; ++r) {
                int row = s * 16 + qd * 4 + r;
                float u0 = acc0[r] + bias0; u0 = u0 > 0.f ? u0 : 0.f;
                float u1 = acc1[r] + bias1; u1 = u1 > 0.f ? u1 : 0.f;
                bufA[row * STR + c0] = f2bf(u0);
                bufA[row * STR + c1] = f2bf(u1);
            }
        }
    }
    __syncthreads();

    // ---- layer 3 (K=128): bufA -> registers, +b3, NO relu ----
    float acc3v[8][2][4];
    {
        bf16x8 wb[2][4];
        #pragma unroll
        for (int t = 0; t < 2; ++t)
            #pragma unroll
            for (int kk = 0; kk < 4; ++kk)
                wb[t][kk] = *(const bf16x8*)(w3t + (wv * 32 + t * 16 + l15) * 128 + kk * 32 + qd * 8);
        float bias0 = lb3[c0], bias1 = lb3[c1];
        #pragma unroll
        for (int s = 0; s < 8; ++s) {
            f32x4 acc0 = {0.f, 0.f, 0.f, 0.f}, acc1 = {0.f, 0.f, 0.f, 0.f};
            #pragma unroll
            for (int kk = 0; kk < 4; ++kk) {
                bf16x8 a = *(const bf16x8*)(bufA + (s * 16 + l15) * STR + kk * 32 + qd * 8);
                acc0 = __builtin_amdgcn_mfma_f32_16x16x32_bf16(a, wb[0][kk], acc0, 0, 0, 0);
                acc1 = __builtin_amdgcn_mfma_f32_16x16x32_bf16(a, wb[1][kk], acc1, 0, 0, 0);
            }
            #pragma unroll
            for (int r = 0; r < 4; ++r) {
                acc3v[s][0][r] = acc0[r] + bias0;
                acc3v[s][1][r] = acc1[r] + bias1;
            }
        }
    }
    __syncthreads();   // everyone done reading bufA before smem is reused as fp32 h3

    // ---- spill h3 fp32 into (whole) smem, stride 132 ----
    #pragma unroll
    for (int s = 0; s < 8; ++s)
        #pragma unroll
        for (int r = 0; r < 4; ++r) {
            int row = s * 16 + qd * 4 + r;
            h3[row * 132 + c0] = acc3v[s][0][r];
            h3[row * 132 + c1] = acc3v[s][1][r];
        }
    __syncthreads();

    // ---- in-block segment reduce (index sorted -> contiguous runs), then atomics ----
    {
        int half = tid >> 7;            // 0: rows 0..63, 1: rows 64..127
        int c = tid & 127;
        int r = half * 64, end = r + 64;
        int cur = segs[r];
        float run = 0.f;
        for (; r < end; ++r) {
            int sg = segs[r];           // wave-uniform -> no divergence
            if (sg != cur) {
                atomicAdd(agg + (size_t)cur * EMB + c, run);
                run = 0.f; cur = sg;
            }
            run += h3[r * 132 + c];
        }
        atomicAdd(agg + (size_t)cur * EMB + c, run);
    }
}

// ---------------- Kernel C: global MLP + log_softmax (fp32, tiny) ----------------
// Block: 256 threads, 32 segments. LDS acts only; weights streamed from global (L1/L2-resident).
__global__ __launch_bounds__(256) void global_mlp(
    const float* __restrict__ agg,
    const float* __restrict__ gW1, const float* __restrict__ gb1,
    const float* __restrict__ gW2, const float* __restrict__ gb2,
    const float* __restrict__ gW3, const float* __restrict__ gb3,
    float* __restrict__ out)
{
    __shared__ float actA[32 * 128];
    __shared__ float actB[32 * 128];
    __shared__ float sc[32 * 32];
    const int tid = threadIdx.x;
    const int s0 = blockIdx.x * 32;

    #pragma unroll
    for (int i = 0; i < 16; ++i) {
        int f = i * 256 + tid;
        actA[f] = agg[(size_t)s0 * 128 + f];
    }
    __syncthreads();

    const int j = tid & 127, sb = tid >> 7;
    // g1: relu(agg @ gW1 + gb1)
    for (int s = sb; s < 32; s += 2) {
        float sum = gb1[j];
        #pragma unroll 8
        for (int k = 0; k < 128; ++k) sum += actA[s * 128 + k] * gW1[k * 128 + j];
        actB[s * 128 + j] = sum > 0.f ? sum : 0.f;
    }
    __syncthreads();
    // g2
    for (int s = sb; s < 32; s += 2) {
        float sum = gb2[j];
        #pragma unroll 8
        for (int k = 0; k < 128; ++k) sum += actB[s * 128 + k] * gW2[k * 128 + j];
        actA[s * 128 + j] = sum > 0.f ? sum : 0.f;
    }
    __syncthreads();
    // g3: scores
    {
        int c = tid & 31, s2 = tid >> 5;
        for (int s = s2; s < 32; s += 8) {
            float sum = gb3[c];
            #pragma unroll 8
            for (int k = 0; k < 128; ++k) sum += actA[s * 128 + k] * gW3[k * 32 + c];
            sc[s * 32 + c] = sum;
        }
    }
    __syncthreads();
    // log_softmax per segment row
    if (tid < 32) {
        float m = -1e30f;
        for (int i = 0; i < 32; ++i) m = fmaxf(m, sc[tid * 32 + i]);
        float l = 0.f;
        for (int i = 0; i < 32; ++i) l += expf(sc[tid * 32 + i] - m);
        l = logf(l) + m;
        for (int i = 0; i < 32; ++i) out[(size_t)(s0 + tid) * 32 + i] = sc[tid * 32 + i] - l;
    }
}

extern "C" void kernel_launch(void* const* d_in, const int* in_sizes, int n_in,
                              void* d_out, int out_size, void* d_ws, size_t ws_size,
                              hipStream_t stream) {
    const float* x   = (const float*)d_in[0];
    const int*   idx = (const int*)d_in[1];
    const float* lW1 = (const float*)d_in[2];
    const float* lb1 = (const float*)d_in[3];
    const float* lW2 = (const float*)d_in[4];
    const float* lb2 = (const float*)d_in[5];
    const float* lW3 = (const float*)d_in[6];
    const float* lb3 = (const float*)d_in[7];
    const float* gW1 = (const float*)d_in[8];
    const float* gb1 = (const float*)d_in[9];
    const float* gW2 = (const float*)d_in[10];
    const float* gb2 = (const float*)d_in[11];
    const float* gW3 = (const float*)d_in[12];
    const float* gb3 = (const float*)d_in[13];
    float* out = (float*)d_out;

    float* agg = (float*)d_ws;                                  // [4096][128] fp32 = 2 MB
    u16* w1t = (u16*)((char*)d_ws + (size_t)NUM_ELEC * EMB * 4);
    u16* w2t = w1t + 128 * 32;
    u16* w3t = w2t + 128 * 128;

    hipMemsetAsync(d_ws, 0, (size_t)NUM_ELEC * EMB * sizeof(float), stream);
    prep_weights<<<64, 256, 0, stream>>>(lW1, lW2, lW3, w1t, w2t, w3t);
    local_fused<<<N_VOTERS / 128, 256, 0, stream>>>(x, idx, lb1, lb2, lb3, w1t, w2t, w3t, agg);
    global_mlp<<<NUM_ELEC / 32, 256, 0, stream>>>(agg, gW1, gb1, gW2, gb2, gW3, gb3, out);
}

// Round 2
// 352.453 us; speedup vs baseline: 1.4150x; 1.4150x over previous
//
#include <hip/hip_runtime.h>
#include <hip/hip_bf16.h>
#include <math.h>

#define N_VOTERS 1048576
#define NUM_CAND 32
#define EMB 128
#define NUM_ELEC 4096

typedef unsigned short u16;
typedef unsigned int u32;
typedef __attribute__((ext_vector_type(8))) short bf16x8;
typedef __attribute__((ext_vector_type(4))) short short4v;
typedef __attribute__((ext_vector_type(4))) float f32x4;

__device__ __forceinline__ u16 f2bf(float f) {   // RNE (used once, in prep)
    union { float f; u32 u; } v; v.f = f;
    u32 r = v.u + 0x7FFFu + ((v.u >> 16) & 1u);
    return (u16)(r >> 16);
}
// pack two floats to bf16 (round-half-up, unbiased for our data): f0 -> low16, f1 -> high16
__device__ __forceinline__ u32 pkbf(float f0, float f1) {
    u32 u0 = __float_as_uint(f0) + 0x8000u;
    u32 u1 = __float_as_uint(f1) + 0x8000u;
    return __builtin_amdgcn_perm(u1, u0, 0x07060302u);   // [u1.hi16 | u0.hi16]
}

// ---------------- Kernel A: transpose+convert local weights to bf16 ----------------
// w1t: [128][32] = W1^T (out-major); w2t/w3t: [128][128] (out-major)
__global__ void prep_weights(const float* __restrict__ lW1, const float* __restrict__ lW2,
                             const float* __restrict__ lW3,
                             u16* __restrict__ w1t, u16* __restrict__ w2t, u16* __restrict__ w3t) {
    int tid = blockIdx.x * blockDim.x + threadIdx.x;  // 0..16383
    if (tid < 4096) {
        int n = tid >> 5, k = tid & 31;
        w1t[tid] = f2bf(lW1[k * EMB + n]);            // lW1 is [32][128]
    }
    {
        int n = tid >> 7, k = tid & 127;
        w2t[tid] = f2bf(lW2[k * EMB + n]);            // lW2 is [128][128]
        w3t[tid] = f2bf(lW3[k * EMB + n]);
    }
}

// ---------------- Kernel B: fused local MLP (weights=A, acts=B) + in-block segment sum ----
// Block: 256 thr = 4 waves, 64 voters. Wave wv owns features wv*32..wv*32+31 (2 m-tiles),
// iterates all 4 voter n-tiles. D layout (col=lane&15=voter, row=qd*4+r=feature) makes the
// epilogue one b64 LDS write of 4 consecutive features per tile.
__global__ __launch_bounds__(256, 4) void local_fused(
    const float* __restrict__ x, const int* __restrict__ idx,
    const float* __restrict__ lb1, const float* __restrict__ lb2, const float* __restrict__ lb3,
    const u16* __restrict__ w1t, const u16* __restrict__ w2t, const u16* __restrict__ w3t,
    float* __restrict__ agg)
{
    constexpr int XSTR = 36;   // x tile stride (72B rows: 8B-aligned for b64 reads)
    constexpr int ASTR = 136;  // act stride (272B rows: 16B-aligned for b128 reads)
    constexpr int HSTR = 132;  // fp32 h3 overlay stride (odd dword stride -> conflict-free col reads)
    __shared__ __align__(16) u16 smem[64 * XSTR + 2 * 64 * ASTR];   // 39424 B
    __shared__ int segs[64];
    u16* bufX = smem;
    u16* act1 = smem + 64 * XSTR;
    u16* act2 = act1 + 64 * ASTR;
    float* h3 = (float*)smem;   // 64*132*4 = 33792 B, overlays everything (all dead by then)

    const int tid = threadIdx.x;
    const int v0 = blockIdx.x * 64;
    const int lane = tid & 63;
    const int wv = tid >> 6;
    const int qd = lane >> 4;
    const int l15 = lane & 15;
    const int mrow0 = wv * 32 + l15;      // weight row for m-tile t=0 (t=1: +16)

    // ---- stage x [64][32] fp32 -> bf16 LDS ----
    {
        const float4* xin = (const float4*)(x + (size_t)v0 * NUM_CAND);
        #pragma unroll
        for (int i = 0; i < 2; ++i) {
            int F = i * 256 + tid;               // float4 id 0..511
            float4 v = xin[F];
            int row = F >> 3, c4 = (F & 7) * 4;
            uint2 pv; pv.x = pkbf(v.x, v.y); pv.y = pkbf(v.z, v.w);
            *(uint2*)(bufX + row * XSTR + c4) = pv;
        }
        if (tid < 64) segs[tid] = idx[v0 + tid];
    }

    // layer-1 weights/bias (issued before barrier to overlap latency)
    bf16x8 wa0 = *(const bf16x8*)(w1t + mrow0 * 32 + qd * 8);
    bf16x8 wa1 = *(const bf16x8*)(w1t + (mrow0 + 16) * 32 + qd * 8);
    float4 bA1 = *(const float4*)(lb1 + wv * 32 + qd * 4);
    float4 bB1 = *(const float4*)(lb1 + wv * 32 + 16 + qd * 4);
    __syncthreads();

    // ---- layer 1 (K=32): bufX -> act1 ----
    #pragma unroll
    for (int nt = 0; nt < 4; ++nt) {
        int vr = nt * 16 + l15;
        union { bf16x8 v; short4v h[2]; } b;
        b.h[0] = *(const short4v*)(bufX + vr * XSTR + qd * 8);
        b.h[1] = *(const short4v*)(bufX + vr * XSTR + qd * 8 + 4);
        f32x4 z = {0.f, 0.f, 0.f, 0.f};
        f32x4 a0 = __builtin_amdgcn_mfma_f32_16x16x32_bf16(wa0, b.v, z, 0, 0, 0);
        f32x4 a1 = __builtin_amdgcn_mfma_f32_16x16x32_bf16(wa1, b.v, z, 0, 0, 0);
        uint2 s0; s0.x = pkbf(fmaxf(a0[0] + bA1.x, 0.f), fmaxf(a0[1] + bA1.y, 0.f));
        s0.y = pkbf(fmaxf(a0[2] + bA1.z, 0.f), fmaxf(a0[3] + bA1.w, 0.f));
        *(uint2*)(act1 + vr * ASTR + wv * 32 + qd * 4) = s0;
        uint2 s1; s1.x = pkbf(fmaxf(a1[0] + bB1.x, 0.f), fmaxf(a1[1] + bB1.y, 0.f));
        s1.y = pkbf(fmaxf(a1[2] + bB1.z, 0.f), fmaxf(a1[3] + bB1.w, 0.f));
        *(uint2*)(act1 + vr * ASTR + wv * 32 + 16 + qd * 4) = s1;
    }

    // layer-2 weights/bias
    bf16x8 w2a[2][4];
    #pragma unroll
    for (int t = 0; t < 2; ++t)
        #pragma unroll
        for (int kk = 0; kk < 4; ++kk)
            w2a[t][kk] = *(const bf16x8*)(w2t + (mrow0 + t * 16) * 128 + kk * 32 + qd * 8);
    float4 bA2 = *(const float4*)(lb2 + wv * 32 + qd * 4);
    float4 bB2 = *(const float4*)(lb2 + wv * 32 + 16 + qd * 4);
    __syncthreads();

    // ---- layer 2 (K=128): act1 -> act2 ----
    #pragma unroll
    for (int nt = 0; nt < 4; ++nt) {
        int vr = nt * 16 + l15;
        f32x4 a0 = {0.f, 0.f, 0.f, 0.f}, a1 = {0.f, 0.f, 0.f, 0.f};
        #pragma unroll
        for (int kk = 0; kk < 4; ++kk) {
            bf16x8 b = *(const bf16x8*)(act1 + vr * ASTR + kk * 32 + qd * 8);
            a0 = __builtin_amdgcn_mfma_f32_16x16x32_bf16(w2a[0][kk], b, a0, 0, 0, 0);
            a1 = __builtin_amdgcn_mfma_f32_16x16x32_bf16(w2a[1][kk], b, a1, 0, 0, 0);
        }
        uint2 s0; s0.x = pkbf(fmaxf(a0[0] + bA2.x, 0.f), fmaxf(a0[1] + bA2.y, 0.f));
        s0.y = pkbf(fmaxf(a0[2] + bA2.z, 0.f), fmaxf(a0[3] + bA2.w, 0.f));
        *(uint2*)(act2 + vr * ASTR + wv * 32 + qd * 4) = s0;
        uint2 s1; s1.x = pkbf(fmaxf(a1[0] + bB2.x, 0.f), fmaxf(a1[1] + bB2.y, 0.f));
        s1.y = pkbf(fmaxf(a1[2] + bB2.z, 0.f), fmaxf(a1[3] + bB2.w, 0.f));
        *(uint2*)(act2 + vr * ASTR + wv * 32 + 16 + qd * 4) = s1;
    }

    // layer-3 weights/bias
    bf16x8 w3a[2][4];
    #pragma unroll
    for (int t = 0; t < 2; ++t)
        #pragma unroll
        for (int kk = 0; kk < 4; ++kk)
            w3a[t][kk] = *(const bf16x8*)(w3t + (mrow0 + t * 16) * 128 + kk * 32 + qd * 8);
    float4 bA3 = *(const float4*)(lb3 + wv * 32 + qd * 4);
    float4 bB3 = *(const float4*)(lb3 + wv * 32 + 16 + qd * 4);
    __syncthreads();

    // ---- layer 3 (K=128): act2 -> regs (+bias, no relu) ----
    f32x4 c3[4][2];
    #pragma unroll
    for (int nt = 0; nt < 4; ++nt) {
        int vr = nt * 16 + l15;
        f32x4 a0 = {0.f, 0.f, 0.f, 0.f}, a1 = {0.f, 0.f, 0.f, 0.f};
        #pragma unroll
        for (int kk = 0; kk < 4; ++kk) {
            bf16x8 b = *(const bf16x8*)(act2 + vr * ASTR + kk * 32 + qd * 8);
            a0 = __builtin_amdgcn_mfma_f32_16x16x32_bf16(w3a[0][kk], b, a0, 0, 0, 0);
            a1 = __builtin_amdgcn_mfma_f32_16x16x32_bf16(w3a[1][kk], b, a1, 0, 0, 0);
        }
        c3[nt][0] = a0; c3[nt][1] = a1;
    }
    __syncthreads();   // all act2 reads done before h3 overlay clobbers smem

    // ---- spill h3 fp32 (one float4 per tile per lane) ----
    #pragma unroll
    for (int nt = 0; nt < 4; ++nt) {
        int vr = nt * 16 + l15;
        float4 q0; q0.x = c3[nt][0][0] + bA3.x; q0.y = c3[nt][0][1] + bA3.y;
        q0.z = c3[nt][0][2] + bA3.z; q0.w = c3[nt][0][3] + bA3.w;
        *(float4*)(h3 + vr * HSTR + wv * 32 + qd * 4) = q0;
        float4 q1; q1.x = c3[nt][1][0] + bB3.x; q1.y = c3[nt][1][1] + bB3.y;
        q1.z = c3[nt][1][2] + bB3.z; q1.w = c3[nt][1][3] + bB3.w;
        *(float4*)(h3 + vr * HSTR + wv * 32 + 16 + qd * 4) = q1;
    }
    __syncthreads();

    // ---- segment reduce (sorted index -> contiguous runs), one atomic per run ----
    {
        int c = tid & 127, h = tid >> 7;
        int r = h * 32, end = r + 32;
        int cur = segs[r];
        float run = 0.f;
        for (; r < end; ++r) {
            int sg = segs[r];             // wave-uniform
            if (sg != cur) {
                atomicAdd(agg + (size_t)cur * EMB + c, run);
                run = 0.f; cur = sg;
            }
            run += h3[r * HSTR + c];
        }
        atomicAdd(agg + (size_t)cur * EMB + c, run);
    }
}

// ---------------- Kernel C: global MLP + log_softmax (fp32) ----------------
// 512 blocks x 256 threads, 8 segments/block. k-outer loop: 1 weight load feeds 4 seg FMAs.
__global__ __launch_bounds__(256) void global_mlp(
    const float* __restrict__ agg,
    const float* __restrict__ gW1, const float* __restrict__ gb1,
    const float* __restrict__ gW2, const float* __restrict__ gb2,
    const float* __restrict__ gW3, const float* __restrict__ gb3,
    float* __restrict__ out)
{
    __shared__ float actA[8 * 128];
    __shared__ float actB[8 * 128];
    __shared__ float sc[8 * 32];
    const int tid = threadIdx.x;
    const int s0 = blockIdx.x * 8;

    #pragma unroll
    for (int i = 0; i < 4; ++i) {
        int f = i * 256 + tid;
        actA[f] = agg[(size_t)s0 * 128 + f];
    }
    __syncthreads();

    const int j = tid & 127, g = tid >> 7;     // g: 0..1, 4 segments each
    // g1
    {
        float acc[4];
        #pragma unroll
        for (int si = 0; si < 4; ++si) acc[si] = gb1[j];
        #pragma unroll 8
        for (int k = 0; k < 128; ++k) {
            float w = gW1[k * 128 + j];
            #pragma unroll
            for (int si = 0; si < 4; ++si) acc[si] += actA[(g * 4 + si) * 128 + k] * w;
        }
        #pragma unroll
        for (int si = 0; si < 4; ++si) actB[(g * 4 + si) * 128 + j] = fmaxf(acc[si], 0.f);
    }
    __syncthreads();
    // g2
    {
        float acc[4];
        #pragma unroll
        for (int si = 0; si < 4; ++si) acc[si] = gb2[j];
        #pragma unroll 8
        for (int k = 0; k < 128; ++k) {
            float w = gW2[k * 128 + j];
            #pragma unroll
            for (int si = 0; si < 4; ++si) acc[si] += actB[(g * 4 + si) * 128 + k] * w;
        }
        #pragma unroll
        for (int si = 0; si < 4; ++si) actA[(g * 4 + si) * 128 + j] = fmaxf(acc[si], 0.f);
    }
    __syncthreads();
    // g3: scores [8][32]
    {
        int c = tid & 31, sg = tid >> 5;       // 8 groups, 1 segment each
        float a3 = gb3[c];
        #pragma unroll 8
        for (int k = 0; k < 128; ++k) a3 += actA[sg * 128 + k] * gW3[k * 32 + c];
        sc[sg * 32 + c] = a3;
    }
    __syncthreads();
    // log_softmax: 32-lane groups, shuffle reduce
    {
        int c = tid & 31, sg = tid >> 5;
        float v = sc[sg * 32 + c];
        float m = v;
        #pragma unroll
        for (int off = 16; off >= 1; off >>= 1) m = fmaxf(m, __shfl_xor(m, off, 32));
        float e = expf(v - m);
        float sum = e;
        #pragma unroll
        for (int off = 16; off >= 1; off >>= 1) sum += __shfl_xor(sum, off, 32);
        out[(size_t)(s0 + sg) * 32 + c] = (v - m) - logf(sum);
    }
}

extern "C" void kernel_launch(void* const* d_in, const int* in_sizes, int n_in,
                              void* d_out, int out_size, void* d_ws, size_t ws_size,
                              hipStream_t stream) {
    const float* x   = (const float*)d_in[0];
    const int*   idx = (const int*)d_in[1];
    const float* lW1 = (const float*)d_in[2];
    const float* lb1 = (const float*)d_in[3];
    const float* lW2 = (const float*)d_in[4];
    const float* lb2 = (const float*)d_in[5];
    const float* lW3 = (const float*)d_in[6];
    const float* lb3 = (const float*)d_in[7];
    const float* gW1 = (const float*)d_in[8];
    const float* gb1 = (const float*)d_in[9];
    const float* gW2 = (const float*)d_in[10];
    const float* gb2 = (const float*)d_in[11];
    const float* gW3 = (const float*)d_in[12];
    const float* gb3 = (const float*)d_in[13];
    float* out = (float*)d_out;

    float* agg = (float*)d_ws;                                  // [4096][128] fp32 = 2 MB
    u16* w1t = (u16*)((char*)d_ws + (size_t)NUM_ELEC * EMB * 4);
    u16* w2t = w1t + 128 * 32;
    u16* w3t = w2t + 128 * 128;

    hipMemsetAsync(d_ws, 0, (size_t)NUM_ELEC * EMB * sizeof(float), stream);
    prep_weights<<<64, 256, 0, stream>>>(lW1, lW2, lW3, w1t, w2t, w3t);
    local_fused<<<N_VOTERS / 64, 256, 0, stream>>>(x, idx, lb1, lb2, lb3, w1t, w2t, w3t, agg);
    global_mlp<<<NUM_ELEC / 8, 256, 0, stream>>>(agg, gW1, gb1, gW2, gb2, gW3, gb3, out);
}